// Round 19
// baseline (65.561 us; speedup 1.0000x reference)
//
#include <hip/hip_runtime.h>

// Mixture-of-64-tiny-experts, fp32.
// R18: extend R17's winning axis. 4 samples/thread vs one weight fetch
// (s_load traffic per sample halves again vs R17), 4 independent chains
// per wave for in-wave latency hiding (grid supplies only 2 waves/SIMD).
// Math = R16/R17 folded form: L1 emits pre-scaled s', tanhshrink folded
// into split L2 weights, output tanh folded into the softmax epilogue.

#define NSUB 64
#define L2E  1.4426950408889634f   // log2(e)
#define L2E2 2.8853900817779268f   // 2*log2(e)

typedef float v2f __attribute__((ext_vector_type(2)));

__device__ __forceinline__ v2f pk_fma(v2f a, v2f b, v2f c) {
    return __builtin_elementwise_fma(a, b, c);
}
__device__ __forceinline__ v2f sp(float s) { return v2f{s, s}; }

// u = rcp(exp2(z)+1), both halves. Overflow-safe at +-inf.
__device__ __forceinline__ v2f sig_u(v2f z) {
    v2f e;
    e.x = __builtin_amdgcn_exp2f(z.x);
    e.y = __builtin_amdgcn_exp2f(z.y);
    v2f ep = e + 1.0f;
    v2f u;
    u.x = __builtin_amdgcn_rcpf(ep.x);
    u.y = __builtin_amdgcn_rcpf(ep.y);
    return u;
}

// Pack per subnet-PAIR p (p, p+32), stride 128 floats = 64 v2f slots
// (R16 layout):
// [0:24)  W1' = 2L*W1 (j*6+i)     [24:28) b1' = 2L*b1
// [28:36) W2s = W2 (o*4+j)        [36:44) W2u = 4L*W2 (o*4+j)
// [44:46) b2'' = 2L*(b2 - sum_j W2[o][j])
// [46:52) Gw2*L                   [52] Gb2*L        [53:64) pad
__global__ void pack_kernel(const float* __restrict__ W1, const float* __restrict__ b1,
                            const float* __restrict__ W2, const float* __restrict__ b2,
                            const float* __restrict__ Gw2, const float* __restrict__ Gb2,
                            float* __restrict__ ws)
{
    int p = threadIdx.x;
    if (p >= 32) return;
    int sa = p, sb = p + 32;
    float* f = ws + p * 128;
    for (int i = 0; i < 24; ++i) { f[2*i]   = W1[sa*24+i]*L2E2;  f[2*i+1]   = W1[sb*24+i]*L2E2; }
    for (int i = 0; i < 4;  ++i) { f[48+2*i] = b1[sa*4+i]*L2E2;  f[48+2*i+1] = b1[sb*4+i]*L2E2; }
    for (int i = 0; i < 8;  ++i) { f[56+2*i] = W2[sa*8+i];       f[56+2*i+1] = W2[sb*8+i]; }
    for (int i = 0; i < 8;  ++i) { f[72+2*i] = W2[sa*8+i]*(2.0f*L2E2);
                                   f[72+2*i+1] = W2[sb*8+i]*(2.0f*L2E2); }
    for (int o = 0; o < 2; ++o) {
        float rsA = 0.f, rsB = 0.f;
        for (int j = 0; j < 4; ++j) { rsA += W2[sa*8+o*4+j]; rsB += W2[sb*8+o*4+j]; }
        f[88+2*o]   = (b2[sa*2+o] - rsA) * L2E2;
        f[88+2*o+1] = (b2[sb*2+o] - rsB) * L2E2;
    }
    for (int i = 0; i < 6;  ++i) { f[92+2*i] = Gw2[sa*6+i]*L2E;  f[92+2*i+1] = Gw2[sb*6+i]*L2E; }
    f[104] = Gb2[sa]*L2E; f[105] = Gb2[sb]*L2E;
    for (int i = 106; i < 128; ++i) f[i] = 0.f;
}

// One subnet-pair step for one sample (R16 folded math). Scalar xs/ga inputs
// (compiler broadcasts via VOP3P op_sel without extra movs).
__device__ __forceinline__ void step(const v2f* __restrict__ f2,
                                     const float* __restrict__ xs,
                                     const float* __restrict__ ga,
                                     v2f& accE, v2f& accU0, v2f& accU1)
{
    v2f s0 = pk_fma(f2[0],  sp(xs[0]), f2[24]);
    v2f s1 = pk_fma(f2[6],  sp(xs[0]), f2[25]);
    v2f s2 = pk_fma(f2[12], sp(xs[0]), f2[26]);
    v2f s3 = pk_fma(f2[18], sp(xs[0]), f2[27]);
#pragma unroll
    for (int i = 1; i < 6; ++i) {
        v2f xi = sp(xs[i]);
        s0 = pk_fma(f2[i],      xi, s0);
        s1 = pk_fma(f2[6 + i],  xi, s1);
        s2 = pk_fma(f2[12 + i], xi, s2);
        s3 = pk_fma(f2[18 + i], xi, s3);
    }

    v2f u0 = sig_u(s0);
    v2f u1 = sig_u(s1);
    v2f u2 = sig_u(s2);
    v2f u3 = sig_u(s3);

    v2f q0 = pk_fma(f2[28], s0, f2[44]);
    q0 = pk_fma(f2[29], s1, q0);
    q0 = pk_fma(f2[30], s2, q0);
    q0 = pk_fma(f2[31], s3, q0);
    q0 = pk_fma(f2[36], u0, q0);
    q0 = pk_fma(f2[37], u1, q0);
    q0 = pk_fma(f2[38], u2, q0);
    q0 = pk_fma(f2[39], u3, q0);

    v2f q1 = pk_fma(f2[32], s0, f2[45]);
    q1 = pk_fma(f2[33], s1, q1);
    q1 = pk_fma(f2[34], s2, q1);
    q1 = pk_fma(f2[35], s3, q1);
    q1 = pk_fma(f2[40], u0, q1);
    q1 = pk_fma(f2[41], u1, q1);
    q1 = pk_fma(f2[42], u2, q1);
    q1 = pk_fma(f2[43], u3, q1);

    v2f uo0 = sig_u(q0);
    v2f uo1 = sig_u(q1);

    v2f la = pk_fma(f2[46], sp(ga[0]), f2[52]);
    la = pk_fma(f2[47], sp(ga[1]), la);
    la = pk_fma(f2[48], sp(ga[2]), la);
    la = pk_fma(f2[49], sp(ga[3]), la);
    la = pk_fma(f2[50], sp(ga[4]), la);
    la = pk_fma(f2[51], sp(ga[5]), la);
    v2f ea;
    ea.x = __builtin_amdgcn_exp2f(la.x);
    ea.y = __builtin_amdgcn_exp2f(la.y);

    accE  = accE + ea;
    accU0 = pk_fma(ea, uo0, accU0);
    accU1 = pk_fma(ea, uo1, accU1);
}

__global__ __launch_bounds__(256) void moe_kernel(
    const float* __restrict__ x,
    const float* __restrict__ wpack,
    const float* __restrict__ Gw1, const float* __restrict__ Gb1,
    float* __restrict__ out)
{
    long t = blockIdx.x * blockDim.x + threadIdx.x;

    // four samples per thread: 24 floats = 6 x float4 (96B stride, aligned)
    const float4* xv = (const float4*)(x + t * 24);
    float4 v0 = xv[0], v1 = xv[1], v2 = xv[2], v3 = xv[3], v4 = xv[4], v5 = xv[5];
    float xs[4][6] = {
        {v0.x, v0.y, v0.z, v0.w, v1.x, v1.y},
        {v1.z, v1.w, v2.x, v2.y, v2.z, v2.w},
        {v3.x, v3.y, v3.z, v3.w, v4.x, v4.y},
        {v4.z, v4.w, v5.x, v5.y, v5.z, v5.w},
    };

    // ---- gating hidden, packed over sample pairs (0,1) and (2,3) ----
    float ga[4][6];
#pragma unroll
    for (int j = 0; j < 6; ++j) {
        v2f sP = sp(Gb1[j]), sQ = sP;
#pragma unroll
        for (int i = 0; i < 6; ++i) {
            v2f w = sp(Gw1[j * 6 + i]);
            sP = pk_fma(w, v2f{xs[0][i], xs[1][i]}, sP);
            sQ = pk_fma(w, v2f{xs[2][i], xs[3][i]}, sQ);
        }
        v2f uP = sig_u(sP * L2E2);
        v2f uQ = sig_u(sQ * L2E2);
        v2f gP = pk_fma(sp(2.0f), uP, sP - 1.0f);   // tanhshrink
        v2f gQ = pk_fma(sp(2.0f), uQ, sQ - 1.0f);
        ga[0][j] = gP.x; ga[1][j] = gP.y;
        ga[2][j] = gQ.x; ga[3][j] = gQ.y;
    }

    v2f accE[4], U0[4], U1[4];
#pragma unroll
    for (int k = 0; k < 4; ++k) { accE[k] = sp(0.f); U0[k] = sp(0.f); U1[k] = sp(0.f); }

    // ---- 32 iterations; one weight fetch serves 4 samples ----
    for (int p = 0; p < 32; ++p) {
        const v2f* f2 = (const v2f*)(wpack + p * 128);
        step(f2, xs[0], ga[0], accE[0], U0[0], U1[0]);
        step(f2, xs[1], ga[1], accE[1], U0[1], U1[1]);
        step(f2, xs[2], ga[2], accE[2], U0[2], U1[2]);
        step(f2, xs[3], ga[3], accE[3], U0[3], U1[3]);
    }

    // out_o = 1 - 2*(sum ea*uo)/E per sample
    float4 r0, r1;
    {
        float E0 = accE[0].x + accE[0].y, E1 = accE[1].x + accE[1].y;
        float c0 = __builtin_amdgcn_rcpf(E0), c1 = __builtin_amdgcn_rcpf(E1);
        r0.x = fmaf(-2.0f * (U0[0].x + U0[0].y), c0, 1.0f);
        r0.y = fmaf(-2.0f * (U1[0].x + U1[0].y), c0, 1.0f);
        r0.z = fmaf(-2.0f * (U0[1].x + U0[1].y), c1, 1.0f);
        r0.w = fmaf(-2.0f * (U1[1].x + U1[1].y), c1, 1.0f);
    }
    {
        float E2 = accE[2].x + accE[2].y, E3 = accE[3].x + accE[3].y;
        float c2 = __builtin_amdgcn_rcpf(E2), c3 = __builtin_amdgcn_rcpf(E3);
        r1.x = fmaf(-2.0f * (U0[2].x + U0[2].y), c2, 1.0f);
        r1.y = fmaf(-2.0f * (U1[2].x + U1[2].y), c2, 1.0f);
        r1.z = fmaf(-2.0f * (U0[3].x + U0[3].y), c3, 1.0f);
        r1.w = fmaf(-2.0f * (U1[3].x + U1[3].y), c3, 1.0f);
    }
    float4* op = (float4*)&out[t * 8];
    op[0] = r0;
    op[1] = r1;
}

extern "C" void kernel_launch(void* const* d_in, const int* in_sizes, int n_in,
                              void* d_out, int out_size, void* d_ws, size_t ws_size,
                              hipStream_t stream) {
    const float* x   = (const float*)d_in[0];
    const float* W1  = (const float*)d_in[1];
    const float* b1  = (const float*)d_in[2];
    const float* W2  = (const float*)d_in[3];
    const float* b2  = (const float*)d_in[4];
    const float* Gw1 = (const float*)d_in[5];
    const float* Gb1 = (const float*)d_in[6];
    const float* Gw2 = (const float*)d_in[7];
    const float* Gb2 = (const float*)d_in[8];
    float* out = (float*)d_out;
    float* ws  = (float*)d_ws;   // 32*128*4 = 16 KB

    pack_kernel<<<1, 64, 0, stream>>>(W1, b1, W2, b2, Gw2, Gb2, ws);

    // 4 samples/thread -> 131072 threads -> 512 blocks
    const int threads = 256;
    const int blocks = (524288 / 4) / threads;  // 512
    moe_kernel<<<blocks, threads, 0, stream>>>(x, ws, Gw1, Gb1, out);
}